// Round 14
// baseline (233.796 us; speedup 1.0000x reference)
//
#include <hip/hip_runtime.h>

// Shapes (fixed): B=2, S=2048, HS=2048, H=16, KV=4, D=128, g=4

typedef __attribute__((ext_vector_type(8))) short bf16x8;
typedef __attribute__((ext_vector_type(4))) float f32x4;
typedef __attribute__((ext_vector_type(16))) float f32x16;

__device__ __forceinline__ unsigned short f2bf(float x) {
  union { float f; unsigned u; } v; v.f = x;
  unsigned r = v.u + 0x7fffu + ((v.u >> 16) & 1u);  // RN-even
  return (unsigned short)(r >> 16);
}

__device__ __forceinline__ float bf2f(unsigned short h) {
  union { unsigned u; float f; } v; v.u = (unsigned)h << 16;
  return v.f;
}

__device__ __forceinline__ unsigned cvt_pk_bf16(float lo, float hi) {
  unsigned r;
  asm("v_cvt_pk_bf16_f32 %0, %1, %2" : "=v"(r) : "v"(lo), "v"(hi));
  return r;
}

__device__ __forceinline__ void gload_lds16(const void* g, void* l) {
  __builtin_amdgcn_global_load_lds(
      (const __attribute__((address_space(1))) void*)g,
      (__attribute__((address_space(3))) void*)l, 16, 0, 0);
}

// ---------------- fused fp32 -> bf16 converts (one launch, block-uniform ranges) ----
__global__ __launch_bounds__(256) void cvt_all(
    const float4* __restrict__ hs, const float4* __restrict__ wq,
    const float4* __restrict__ wk, const float4* __restrict__ wv,
    const float4* __restrict__ wo, ushort4* __restrict__ X,
    ushort4* __restrict__ Wqkv, ushort4* __restrict__ WoB) {
  int i = blockIdx.x * 256 + threadIdx.x;
  const float4* src;
  ushort4* dst;
  int off;
  if (i < 2097152)      { src = hs; dst = X;               off = 0; }
  else if (i < 3145728) { src = wq; dst = Wqkv;            off = 2097152; }
  else if (i < 3407872) { src = wk; dst = Wqkv + 1048576;  off = 3145728; }
  else if (i < 3670016) { src = wv; dst = Wqkv + 1310720;  off = 3407872; }
  else                  { src = wo; dst = WoB;             off = 3670016; }
  int j = i - off;
  float4 v = src[j];
  dst[j] = make_ushort4(f2bf(v.x), f2bf(v.y), f2bf(v.z), f2bf(v.w));
}

// ---------------- 8-phase GEMM: C[M][N] = sum_k A[m][k]*B[n][k] ----------------
template <int NF, bool OUT_BF16>
__global__ __launch_bounds__(512, 2) void gemm_bt_8ph(
    const unsigned short* __restrict__ A, const unsigned short* __restrict__ Bm,
    void* __restrict__ Cout, int M, int N, int K) {
  __shared__ char lsA[2][32768];          // 2 planes x 16KB per buf
  __shared__ char lsB[2][NF * 8192];      // 2 planes x NF*4KB per buf
  const int tid = threadIdx.x;
  const int wave = tid >> 6, lane = tid & 63;
  const int lrow = lane & 15, kg = lane >> 4;
  const int wm = wave >> 2, wn = wave & 3;
  const int BN = NF * 64;
  const int nbn = N / BN;
  const int bid = (blockIdx.x & 7) * (gridDim.x >> 3) + (blockIdx.x >> 3);
  const int m0 = (bid / nbn) << 8;
  const int n0 = (bid % nbn) * BN;
  const int NT = K >> 6;

  const int srow = tid >> 2;
  const int scol = (((tid & 3) ^ (srow & 3)) << 3);
  const size_t a0 = (size_t)(m0 + srow) * K + scol;
  const size_t a1 = (size_t)(m0 + 128 + srow) * K + scol;
  const size_t b0 = (size_t)(n0 + srow) * K + scol;
  const size_t b1 = (size_t)(n0 + 128 + srow) * K + scol;  // NF==3, tid<256 only

  f32x4 acc[8][NF];
#pragma unroll
  for (int i = 0; i < 8; ++i)
#pragma unroll
    for (int j = 0; j < NF; ++j)
#pragma unroll
      for (int t = 0; t < 4; ++t) acc[i][j][t] = 0.f;

  const int xk = ((kg ^ (lrow & 3)) << 4);
  const int abase = (wm * 128 + lrow) * 64 + xk;
  const int bbase = (wn * NF * 16 + lrow) * 64 + xk;

  auto stage_plane = [&](int T, int ks) {
    if (T >= NT) return;
    const int buf = T & 1;
    const size_t kof = (size_t)T * 64 + ks * 32;
    char* da = lsA[buf] + ks * 16384 + wave * 1024;
    gload_lds16(A + a0 + kof, da);
    gload_lds16(A + a1 + kof, da + 8192);
    char* db = lsB[buf] + ks * (NF * 4096) + wave * 1024;
    gload_lds16(Bm + b0 + kof, db);
    if (NF >= 3) {
      if (tid < 256) gload_lds16(Bm + b1 + kof, db + 8192);
    }
  };

  auto phase = [&](int T, int ks, int sT, int sKs) {
    const int buf = T & 1;
    const char* pa = lsA[buf] + ks * 16384;
    const char* pb = lsB[buf] + ks * (NF * 4096);
    bf16x8 af[8], bfr[NF];
#pragma unroll
    for (int mf = 0; mf < 8; ++mf)
      af[mf] = *(const bf16x8*)(pa + abase + mf * 1024);
#pragma unroll
    for (int nf = 0; nf < NF; ++nf)
      bfr[nf] = *(const bf16x8*)(pb + bbase + nf * 1024);
    stage_plane(sT, sKs);
    asm volatile("s_waitcnt vmcnt(6)" ::: "memory");
    __builtin_amdgcn_s_barrier();
    asm volatile("s_waitcnt lgkmcnt(0)" ::: "memory");
    __builtin_amdgcn_sched_barrier(0);
    __builtin_amdgcn_s_setprio(1);
#pragma unroll
    for (int mf = 0; mf < 8; ++mf)
#pragma unroll
      for (int nf = 0; nf < NF; ++nf)
        acc[mf][nf] =
            __builtin_amdgcn_mfma_f32_16x16x32_bf16(af[mf], bfr[nf], acc[mf][nf], 0, 0, 0);
    __builtin_amdgcn_s_setprio(0);
    __builtin_amdgcn_s_barrier();
  };

  stage_plane(0, 0);
  stage_plane(0, 1);
  stage_plane(1, 0);
  asm volatile("s_waitcnt vmcnt(6)" ::: "memory");
  __builtin_amdgcn_s_barrier();

  for (int kt = 0; kt < NT; ++kt) {
    phase(kt, 0, kt + 1, 1);
    phase(kt, 1, kt + 2, 0);
  }

#pragma unroll
  for (int mf = 0; mf < 8; ++mf) {
#pragma unroll
    for (int nf = 0; nf < NF; ++nf) {
      int row = m0 + wm * 128 + mf * 16 + kg * 4;
      int col = n0 + wn * NF * 16 + nf * 16 + lrow;
      if (OUT_BF16) {
        unsigned short* C = (unsigned short*)Cout;
#pragma unroll
        for (int t = 0; t < 4; ++t)
          C[(size_t)(row + t) * N + col] = f2bf(acc[mf][nf][t]);
      } else {
        float* C = (float*)Cout;
#pragma unroll
        for (int t = 0; t < 4; ++t)
          C[(size_t)(row + t) * N + col] = acc[mf][nf][t];
      }
    }
  }
}

// ---------------- RMSNorm + RoPE + scale; Q linear, K/V as pre-baked 16KB tiles ----
// Tiles cover 64 keys of one (b,kv): tb = ((b*4+kv)*32 + (s>>6)) * 16384 bytes.
// K tile FRAG-MAJOR: s=d>>4, hi=(d>>3)&1, e=d&7:
//   byte = s*2048 + hi*1024 + (key>>5)*512 + (key&31)*16 + e*2
// V tile (B-frag layout): p=key>>4, vhi=(key>>2)&1, e=(key&3)|(((key>>3)&1)<<2)
//   byte = p*4096 + (d>>5)*1024 + vhi*512 + (d&31)*16 + e*2
// Q pre-scaled by D^-1/2 * log2(e)  (softmax in exp2 domain)
__global__ __launch_bounds__(256) void rms_rope(
    const unsigned short* __restrict__ QKV, const float* __restrict__ cosT,
    const float* __restrict__ sinT, const float* __restrict__ wq,
    const float* __restrict__ wk, unsigned short* __restrict__ Q,
    unsigned short* __restrict__ Kg, unsigned short* __restrict__ Vg) {
  int task = blockIdx.x * 4 + (threadIdx.x >> 6);
  int lane = threadIdx.x & 63;
  int row = task / 24;
  int slot = task - row * 24;
  int b = row >> 11, s = row & 2047;
  const unsigned short* x = QKV + (size_t)row * 3072 + slot * 128;
  float x1 = bf2f(x[lane]), x2 = bf2f(x[lane + 64]);
  if (slot < 20) {
    float ss = x1 * x1 + x2 * x2;
#pragma unroll
    for (int msk = 1; msk < 64; msk <<= 1) ss += __shfl_xor(ss, msk);
    float inv = rsqrtf(ss * (1.0f / 128.0f) + 1e-6f);
    const float* w = (slot < 16) ? wq : wk;
    x1 *= inv * w[lane];
    x2 *= inv * w[lane + 64];
    float c1 = cosT[s * 128 + lane], c2 = cosT[s * 128 + lane + 64];
    float sn1 = sinT[s * 128 + lane], sn2 = sinT[s * 128 + lane + 64];
    float o1 = x1 * c1 - x2 * sn1;
    float o2 = x2 * c2 + x1 * sn2;
    if (slot < 16) {
      const float qs = 0.08838834764831845f * 1.4426950408889634f;  // D^-1/2 * log2(e)
      o1 *= qs; o2 *= qs;
    }
    x1 = o1; x2 = o2;
  }
  if (slot < 16) {
    unsigned short* dst = Q + (((size_t)b * 16 + slot) * 2048 + s) * 128;
    dst[lane] = f2bf(x1);
    dst[lane + 64] = f2bf(x2);
  } else {
    int kv = (slot - 16) & 3;
    size_t tb = ((size_t)((b * 4 + kv) * 32) + (s >> 6)) * 16384;
    int key = s & 63;
    if (slot < 20) {
      char* base = (char*)Kg + tb;
      int kb = (key >> 5) * 512 + (key & 31) * 16;
      int d1 = lane, d2 = lane + 64;
      *(unsigned short*)(base + (d1 >> 4) * 2048 + ((d1 >> 3) & 1) * 1024 + kb + (d1 & 7) * 2) = f2bf(x1);
      *(unsigned short*)(base + (d2 >> 4) * 2048 + ((d2 >> 3) & 1) * 1024 + kb + (d2 & 7) * 2) = f2bf(x2);
    } else {
      char* base = (char*)Vg + tb;
      int p = key >> 4;
      int vhi = (key >> 2) & 1;
      int e = (key & 3) | (((key >> 3) & 1) << 2);
      int off = p * 4096 + vhi * 512 + e * 2;
      int d1 = lane, d2 = lane + 64;
      *(unsigned short*)(base + off + (d1 >> 5) * 1024 + (d1 & 31) * 16) = f2bf(x1);
      *(unsigned short*)(base + off + (d2 >> 5) * 1024 + (d2 & 31) * 16) = f2bf(x2);
    }
  }
}

// ---------------- flash attention: 32x32x16, KVBLK=64, split-pipe operands ---------
// K: LDS dbuf (frag-major, contiguous conflict-free reads).
// V: GLOBAL-direct to vr[16] (L2-resident B-frag layout) -> LDS traffic halved,
//    V bytes flow via L1/L2 concurrently with the LDS pipe.
// Fixed-base exp2 softmax; row-denominator via MFMA ones-column (acc4).
// Schedule: softmax(t) | B1 | stage(t+2) || PV(t) | loadV(t+1) | B2 | qk(t+1).
// B1/B2 are raw s_barrier: PV touches no LDS; stage(t+1) retirement is implied
// in-order by PV's compiler-inserted vr vmcnt before B2 publishes.
__global__ __launch_bounds__(256, 2) void attn64(
    const unsigned short* __restrict__ Q, const unsigned short* __restrict__ Kg,
    const unsigned short* __restrict__ Vg, unsigned short* __restrict__ O) {
  __shared__ unsigned short Kl[2][8192];   // 2 x 16KB K tiles (frag-major)
  const int tid = threadIdx.x;
  const int wave = tid >> 6, lane = tid & 63;
  const int l31 = lane & 31, hi = lane >> 5;
  int bid = blockIdx.x;
  bid = (bid & 7) * 64 + (bid >> 3);  // XCD swizzle: 512 % 8 == 0, bijective
  const int bh = bid >> 4, qt = bid & 15;
  const int b = bh >> 4, h = bh & 15, kh = h >> 2;
  const char* Kt = (const char*)Kg + (size_t)(b * 4 + kh) * 524288;
  const char* Vt = (const char*)Vg + (size_t)(b * 4 + kh) * 524288;
  const unsigned short* Qb =
      Q + ((size_t)(b * 16 + h) * 2048 + qt * 128 + wave * 32) * 128;
  bf16x8 qf[8];
#pragma unroll
  for (int s = 0; s < 8; ++s)
    qf[s] = *(const bf16x8*)(Qb + l31 * 128 + s * 16 + hi * 8);
  f32x16 acc[4], acc4;
#pragma unroll
  for (int c = 0; c < 4; ++c)
#pragma unroll
    for (int r = 0; r < 16; ++r) acc[c][r] = 0.f;
#pragma unroll
  for (int r = 0; r < 16; ++r) acc4[r] = 0.f;
  bf16x8 ones;
#pragma unroll
  for (int i = 0; i < 8; ++i) ones[i] = (short)0x3F80;  // bf16 1.0

  const char* Vlane = Vt + hi * 512 + l31 * 16;  // + t*16384 + p*4096 + c*1024
  bf16x8 vr[16];

  auto stageK = [&](int t) {  // 4 async DMA: 16KB K tile into buf t&1
    const char* kt = Kt + (size_t)t * 16384;
    char* kd = (char*)Kl[t & 1];
#pragma unroll
    for (int c = 0; c < 4; ++c)
      gload_lds16(kt + c * 4096 + tid * 16, kd + c * 4096 + wave * 1024);
  };
  auto loadV = [&](int t) {  // 16 coalesced global b128 -> vr
    const char* vt = Vlane + (size_t)t * 16384;
#pragma unroll
    for (int p = 0; p < 4; ++p)
#pragma unroll
      for (int c = 0; c < 4; ++c)
        vr[p * 4 + c] = *(const bf16x8*)(vt + p * 4096 + c * 1024);
  };

  auto qk = [&](int t, f32x16& s0, f32x16& s1) {  // frag-major: contiguous, 0-conflict
    const char* Kb = (const char*)Kl[t & 1] + hi * 1024 + l31 * 16;
#pragma unroll
    for (int r = 0; r < 16; ++r) { s0[r] = 0.f; s1[r] = 0.f; }
    __builtin_amdgcn_s_setprio(1);
#pragma unroll
    for (int s = 0; s < 8; ++s) {
      bf16x8 k0 = *(const bf16x8*)(Kb + s * 2048);
      bf16x8 k1 = *(const bf16x8*)(Kb + s * 2048 + 512);
      s0 = __builtin_amdgcn_mfma_f32_32x32x16_bf16(k0, qf[s], s0, 0, 0, 0);
      s1 = __builtin_amdgcn_mfma_f32_32x32x16_bf16(k1, qf[s], s1, 0, 0, 0);
    }
    __builtin_amdgcn_s_setprio(0);
  };

  // half(t): exp2/pack | B1 | stage(t+2) + PV(t) | loadV(t+1) | B2 | qk(t+1)->N
  auto half = [&](int t, f32x16& c0, f32x16& c1, f32x16& n0_, f32x16& n1_) {
    float p0[16], p1[16];
#pragma unroll
    for (int r = 0; r < 16; ++r) {
      p0[r] = exp2f(c0[r]);
      p1[r] = exp2f(c1[r]);
    }
    union { bf16x8 v[4]; unsigned w[16]; } pa;
#pragma unroll
    for (int r = 0; r < 4; ++r) {
      pa.w[r]      = cvt_pk_bf16(p0[2 * r], p0[2 * r + 1]);
      pa.w[4 + r]  = cvt_pk_bf16(p0[8 + 2 * r], p0[9 + 2 * r]);
      pa.w[8 + r]  = cvt_pk_bf16(p1[2 * r], p1[2 * r + 1]);
      pa.w[12 + r] = cvt_pk_bf16(p1[8 + 2 * r], p1[9 + 2 * r]);
    }
    // B1: all waves past qk(t) (its ds_reads retired before their MFMAs);
    // Kl[t&1] is now dead -> safe to restage.
    __builtin_amdgcn_s_barrier();
    if (t + 2 < 32) stageK(t + 2);       // DMA into Kl[t&1], long window
    __builtin_amdgcn_sched_barrier(0);
    __builtin_amdgcn_s_setprio(1);
#pragma unroll
    for (int p = 0; p < 4; ++p) {        // PV: pure register MFMA (vr via vmcnt)
#pragma unroll
      for (int c = 0; c < 4; ++c)
        acc[c] = __builtin_amdgcn_mfma_f32_32x32x16_bf16(pa.v[p], vr[p * 4 + c], acc[c], 0, 0, 0);
      acc4 = __builtin_amdgcn_mfma_f32_32x32x16_bf16(pa.v[p], ones, acc4, 0, 0, 0);
    }
    __builtin_amdgcn_s_setprio(0);
    if (t + 1 < 32) loadV(t + 1);        // WAR-safe: after PV consumed vr
    // B2: publishes Kl[(t+1)&1] (stage(t+1) retired in-order before PV's vr wait)
    __builtin_amdgcn_s_barrier();
    if (t + 1 < 32) qk(t + 1, n0_, n1_); // loadV(t+1) hides under qk+softmax
  };

  // prologue
  stageK(0);
  stageK(1);
  loadV(0);
  asm volatile("s_waitcnt vmcnt(0)" ::: "memory");
  __builtin_amdgcn_s_barrier();
  f32x16 sA0, sA1, sB0, sB1;
  qk(0, sA0, sA1);

  for (int t = 0; t < 32; t += 2) {
    half(t, sA0, sA1, sB0, sB1);
    half(t + 1, sB0, sB1, sA0, sA1);
  }

  // epilogue: acc[c][r] = N[q][d=c*32+l31], acc4[r] = lsum[q] (same lane, same r)
#pragma unroll
  for (int r = 0; r < 16; ++r) {
    int q = (r & 3) + 8 * (r >> 2) + 4 * hi;
    float invq = 1.0f / acc4[r];
    int srow = qt * 128 + wave * 32 + q;
    unsigned short* dst = O + (((size_t)b * 2048 + srow) * 16 + h) * 128;
#pragma unroll
    for (int c = 0; c < 4; ++c)
      dst[c * 32 + l31] = f2bf(acc[c][r] * invq);
  }
}

extern "C" void kernel_launch(void* const* d_in, const int* in_sizes, int n_in,
                              void* d_out, int out_size, void* d_ws, size_t ws_size,
                              hipStream_t stream) {
  const float* hs   = (const float*)d_in[0];
  const float* cosT = (const float*)d_in[1];
  const float* sinT = (const float*)d_in[2];
  const float* Wq   = (const float*)d_in[3];
  const float* Wk   = (const float*)d_in[4];
  const float* Wv   = (const float*)d_in[5];
  const float* Wo   = (const float*)d_in[6];
  const float* nqw  = (const float*)d_in[7];
  const float* nkw  = (const float*)d_in[8];
  float* out = (float*)d_out;

  char* ws = (char*)d_ws;
  unsigned short* X    = (unsigned short*)ws;               // 4096x2048 bf16
  unsigned short* Wqkv = X + 8388608;                       // 3072x2048 bf16
  unsigned short* WoB  = Wqkv + 6291456;                    // 2048x2048 bf16
  unsigned short* QKVb = WoB + 4194304;                     // 4096x3072 bf16
  unsigned short* Qb   = QKVb + 12582912;                   // (B,H,S,D)
  unsigned short* Kg   = Qb + 8388608;                      // K tiles 4.19MB
  unsigned short* Vg   = Kg + 2097152;                      // V tiles 4.19MB
  unsigned short* Ob   = QKVb;                              // reuse QKVb (dead)

  cvt_all<<<18432, 256, 0, stream>>>((const float4*)hs, (const float4*)Wq,
                                     (const float4*)Wk, (const float4*)Wv,
                                     (const float4*)Wo, (ushort4*)X,
                                     (ushort4*)Wqkv, (ushort4*)WoB);

  // QKV = X @ Wqkv^T : 256x192 tiles -> 16x16 = 256 blocks, bf16 out
  gemm_bt_8ph<3, true><<<256, 512, 0, stream>>>(X, Wqkv, QKVb, 4096, 3072, 2048);

  rms_rope<<<24576, 256, 0, stream>>>(QKVb, cosT, sinT, nqw, nkw, Qb, Kg, Vg);

  attn64<<<512, 256, 0, stream>>>(Qb, Kg, Vg, Ob);

  // out = O @ Wo^T : 256x128 tiles -> 16x16 = 256 blocks, f32 out
  gemm_bt_8ph<2, false><<<256, 512, 0, stream>>>(Ob, WoB, out, 4096, 2048, 2048);
}

// Round 15
// 217.235 us; speedup vs baseline: 1.0762x; 1.0762x over previous
//
#include <hip/hip_runtime.h>

// Shapes (fixed): B=2, S=2048, HS=2048, H=16, KV=4, D=128, g=4

typedef __attribute__((ext_vector_type(8))) short bf16x8;
typedef __attribute__((ext_vector_type(4))) float f32x4;
typedef __attribute__((ext_vector_type(16))) float f32x16;

__device__ __forceinline__ unsigned short f2bf(float x) {
  union { float f; unsigned u; } v; v.f = x;
  unsigned r = v.u + 0x7fffu + ((v.u >> 16) & 1u);  // RN-even
  return (unsigned short)(r >> 16);
}

__device__ __forceinline__ float bf2f(unsigned short h) {
  union { unsigned u; float f; } v; v.u = (unsigned)h << 16;
  return v.f;
}

__device__ __forceinline__ unsigned cvt_pk_bf16(float lo, float hi) {
  unsigned r;
  asm("v_cvt_pk_bf16_f32 %0, %1, %2" : "=v"(r) : "v"(lo), "v"(hi));
  return r;
}

__device__ __forceinline__ void gload_lds16(const void* g, void* l) {
  __builtin_amdgcn_global_load_lds(
      (const __attribute__((address_space(1))) void*)g,
      (__attribute__((address_space(3))) void*)l, 16, 0, 0);
}

// ---------------- fused fp32 -> bf16 converts (one launch, block-uniform ranges) ----
__global__ __launch_bounds__(256) void cvt_all(
    const float4* __restrict__ hs, const float4* __restrict__ wq,
    const float4* __restrict__ wk, const float4* __restrict__ wv,
    const float4* __restrict__ wo, ushort4* __restrict__ X,
    ushort4* __restrict__ Wqkv, ushort4* __restrict__ WoB) {
  int i = blockIdx.x * 256 + threadIdx.x;
  const float4* src;
  ushort4* dst;
  int off;
  if (i < 2097152)      { src = hs; dst = X;               off = 0; }
  else if (i < 3145728) { src = wq; dst = Wqkv;            off = 2097152; }
  else if (i < 3407872) { src = wk; dst = Wqkv + 1048576;  off = 3145728; }
  else if (i < 3670016) { src = wv; dst = Wqkv + 1310720;  off = 3407872; }
  else                  { src = wo; dst = WoB;             off = 3670016; }
  int j = i - off;
  float4 v = src[j];
  dst[j] = make_ushort4(f2bf(v.x), f2bf(v.y), f2bf(v.z), f2bf(v.w));
}

// ---------------- 8-phase GEMM: C[M][N] = sum_k A[m][k]*B[n][k] ----------------
// LDS bank fix (R14): slot swizzle keyed on (row>>1)&3, not (row&3).
// Rows alternate bank-base {0,16} (row stride 64B); equal-parity rows now get
// DISTINCT 16B slots across lrow 0/2/4/6 -> uniform 2-way (free, m136) instead
// of 4-way. Invariant under mf*16/wn*48/wm*128 row offsets (all ≡ 0 mod 8 rows).
template <int NF, bool OUT_BF16>
__global__ __launch_bounds__(512, 2) void gemm_bt_8ph(
    const unsigned short* __restrict__ A, const unsigned short* __restrict__ Bm,
    void* __restrict__ Cout, int M, int N, int K) {
  __shared__ char lsA[2][32768];          // 2 planes x 16KB per buf
  __shared__ char lsB[2][NF * 8192];      // 2 planes x NF*4KB per buf
  const int tid = threadIdx.x;
  const int wave = tid >> 6, lane = tid & 63;
  const int lrow = lane & 15, kg = lane >> 4;
  const int wm = wave >> 2, wn = wave & 3;
  const int BN = NF * 64;
  const int nbn = N / BN;
  const int bid = (blockIdx.x & 7) * (gridDim.x >> 3) + (blockIdx.x >> 3);
  const int m0 = (bid / nbn) << 8;
  const int n0 = (bid % nbn) * BN;
  const int NT = K >> 6;

  const int srow = tid >> 2;
  const int scol = (((tid & 3) ^ ((srow >> 1) & 3)) << 3);  // inverse of read swizzle
  const size_t a0 = (size_t)(m0 + srow) * K + scol;
  const size_t a1 = (size_t)(m0 + 128 + srow) * K + scol;
  const size_t b0 = (size_t)(n0 + srow) * K + scol;
  const size_t b1 = (size_t)(n0 + 128 + srow) * K + scol;  // NF==3, tid<256 only

  f32x4 acc[8][NF];
#pragma unroll
  for (int i = 0; i < 8; ++i)
#pragma unroll
    for (int j = 0; j < NF; ++j)
#pragma unroll
      for (int t = 0; t < 4; ++t) acc[i][j][t] = 0.f;

  const int xk = ((kg ^ ((lrow >> 1) & 3)) << 4);  // bank-fix swizzle
  const int abase = (wm * 128 + lrow) * 64 + xk;
  const int bbase = (wn * NF * 16 + lrow) * 64 + xk;

  auto stage_plane = [&](int T, int ks) {
    if (T >= NT) return;
    const int buf = T & 1;
    const size_t kof = (size_t)T * 64 + ks * 32;
    char* da = lsA[buf] + ks * 16384 + wave * 1024;
    gload_lds16(A + a0 + kof, da);
    gload_lds16(A + a1 + kof, da + 8192);
    char* db = lsB[buf] + ks * (NF * 4096) + wave * 1024;
    gload_lds16(Bm + b0 + kof, db);
    if (NF >= 3) {
      if (tid < 256) gload_lds16(Bm + b1 + kof, db + 8192);
    }
  };

  auto phase = [&](int T, int ks, int sT, int sKs) {
    const int buf = T & 1;
    const char* pa = lsA[buf] + ks * 16384;
    const char* pb = lsB[buf] + ks * (NF * 4096);
    bf16x8 af[8], bfr[NF];
#pragma unroll
    for (int mf = 0; mf < 8; ++mf)
      af[mf] = *(const bf16x8*)(pa + abase + mf * 1024);
#pragma unroll
    for (int nf = 0; nf < NF; ++nf)
      bfr[nf] = *(const bf16x8*)(pb + bbase + nf * 1024);
    stage_plane(sT, sKs);
    asm volatile("s_waitcnt vmcnt(6)" ::: "memory");
    __builtin_amdgcn_s_barrier();
    asm volatile("s_waitcnt lgkmcnt(0)" ::: "memory");
    __builtin_amdgcn_sched_barrier(0);
    __builtin_amdgcn_s_setprio(1);
#pragma unroll
    for (int mf = 0; mf < 8; ++mf)
#pragma unroll
      for (int nf = 0; nf < NF; ++nf)
        acc[mf][nf] =
            __builtin_amdgcn_mfma_f32_16x16x32_bf16(af[mf], bfr[nf], acc[mf][nf], 0, 0, 0);
    __builtin_amdgcn_s_setprio(0);
    __builtin_amdgcn_s_barrier();
  };

  stage_plane(0, 0);
  stage_plane(0, 1);
  stage_plane(1, 0);
  asm volatile("s_waitcnt vmcnt(6)" ::: "memory");
  __builtin_amdgcn_s_barrier();

  for (int kt = 0; kt < NT; ++kt) {
    phase(kt, 0, kt + 1, 1);
    phase(kt, 1, kt + 2, 0);
  }

#pragma unroll
  for (int mf = 0; mf < 8; ++mf) {
#pragma unroll
    for (int nf = 0; nf < NF; ++nf) {
      int row = m0 + wm * 128 + mf * 16 + kg * 4;
      int col = n0 + wn * NF * 16 + nf * 16 + lrow;
      if (OUT_BF16) {
        unsigned short* C = (unsigned short*)Cout;
#pragma unroll
        for (int t = 0; t < 4; ++t)
          C[(size_t)(row + t) * N + col] = f2bf(acc[mf][nf][t]);
      } else {
        float* C = (float*)Cout;
#pragma unroll
        for (int t = 0; t < 4; ++t)
          C[(size_t)(row + t) * N + col] = acc[mf][nf][t];
      }
    }
  }
}

// ---------------- RMSNorm + RoPE + scale; Q linear, K/V as pre-baked 16KB tiles ----
// Tiles cover 64 keys of one (b,kv): tb = ((b*4+kv)*32 + (s>>6)) * 16384 bytes.
// K tile FRAG-MAJOR: s=d>>4, hi=(d>>3)&1, e=d&7:
//   byte = s*2048 + hi*1024 + (key>>5)*512 + (key&31)*16 + e*2
// V tile (B-frag layout): p=key>>4, vhi=(key>>2)&1, e=(key&3)|(((key>>3)&1)<<2)
//   byte = p*4096 + (d>>5)*1024 + vhi*512 + (d&31)*16 + e*2
// Q pre-scaled by D^-1/2 * log2(e)  (softmax in exp2 domain)
__global__ __launch_bounds__(256) void rms_rope(
    const unsigned short* __restrict__ QKV, const float* __restrict__ cosT,
    const float* __restrict__ sinT, const float* __restrict__ wq,
    const float* __restrict__ wk, unsigned short* __restrict__ Q,
    unsigned short* __restrict__ Kg, unsigned short* __restrict__ Vg) {
  int task = blockIdx.x * 4 + (threadIdx.x >> 6);
  int lane = threadIdx.x & 63;
  int row = task / 24;
  int slot = task - row * 24;
  int b = row >> 11, s = row & 2047;
  const unsigned short* x = QKV + (size_t)row * 3072 + slot * 128;
  float x1 = bf2f(x[lane]), x2 = bf2f(x[lane + 64]);
  if (slot < 20) {
    float ss = x1 * x1 + x2 * x2;
#pragma unroll
    for (int msk = 1; msk < 64; msk <<= 1) ss += __shfl_xor(ss, msk);
    float inv = rsqrtf(ss * (1.0f / 128.0f) + 1e-6f);
    const float* w = (slot < 16) ? wq : wk;
    x1 *= inv * w[lane];
    x2 *= inv * w[lane + 64];
    float c1 = cosT[s * 128 + lane], c2 = cosT[s * 128 + lane + 64];
    float sn1 = sinT[s * 128 + lane], sn2 = sinT[s * 128 + lane + 64];
    float o1 = x1 * c1 - x2 * sn1;
    float o2 = x2 * c2 + x1 * sn2;
    if (slot < 16) {
      const float qs = 0.08838834764831845f * 1.4426950408889634f;  // D^-1/2 * log2(e)
      o1 *= qs; o2 *= qs;
    }
    x1 = o1; x2 = o2;
  }
  if (slot < 16) {
    unsigned short* dst = Q + (((size_t)b * 16 + slot) * 2048 + s) * 128;
    dst[lane] = f2bf(x1);
    dst[lane + 64] = f2bf(x2);
  } else {
    int kv = (slot - 16) & 3;
    size_t tb = ((size_t)((b * 4 + kv) * 32) + (s >> 6)) * 16384;
    int key = s & 63;
    if (slot < 20) {
      char* base = (char*)Kg + tb;
      int kb = (key >> 5) * 512 + (key & 31) * 16;
      int d1 = lane, d2 = lane + 64;
      *(unsigned short*)(base + (d1 >> 4) * 2048 + ((d1 >> 3) & 1) * 1024 + kb + (d1 & 7) * 2) = f2bf(x1);
      *(unsigned short*)(base + (d2 >> 4) * 2048 + ((d2 >> 3) & 1) * 1024 + kb + (d2 & 7) * 2) = f2bf(x2);
    } else {
      char* base = (char*)Vg + tb;
      int p = key >> 4;
      int vhi = (key >> 2) & 1;
      int e = (key & 3) | (((key >> 3) & 1) << 2);
      int off = p * 4096 + vhi * 512 + e * 2;
      int d1 = lane, d2 = lane + 64;
      *(unsigned short*)(base + off + (d1 >> 5) * 1024 + (d1 & 31) * 16) = f2bf(x1);
      *(unsigned short*)(base + off + (d2 >> 5) * 1024 + (d2 & 31) * 16) = f2bf(x2);
    }
  }
}

// ---------------- flash attention (R12 best): 32x32x16, KVBLK=64, K+V LDS dbuf ----
// Wave owns 32 q-rows. S^T = K*Q^T (lane holds 32 scores of q=lane&31).
// Fixed-base exp2 softmax; row-denominator via MFMA ones-column (acc4).
// Pipeline: softmax(t) | bar1 | PV(t)+sum(t) | bar2 | stage(t+2) | QK(t+1).
__global__ __launch_bounds__(256, 2) void attn64(
    const unsigned short* __restrict__ Q, const unsigned short* __restrict__ Kg,
    const unsigned short* __restrict__ Vg, unsigned short* __restrict__ O) {
  __shared__ unsigned short Kl[2][8192];   // 2 x 16KB K tiles (frag-major)
  __shared__ unsigned short Vl[2][8192];   // 2 x 16KB V tiles (B-frag layout)
  const int tid = threadIdx.x;
  const int wave = tid >> 6, lane = tid & 63;
  const int l31 = lane & 31, hi = lane >> 5;
  int bid = blockIdx.x;
  bid = (bid & 7) * 64 + (bid >> 3);  // XCD swizzle: 512 % 8 == 0, bijective
  const int bh = bid >> 4, qt = bid & 15;
  const int b = bh >> 4, h = bh & 15, kh = h >> 2;
  const char* Kt = (const char*)Kg + (size_t)(b * 4 + kh) * 524288;
  const char* Vt = (const char*)Vg + (size_t)(b * 4 + kh) * 524288;
  const unsigned short* Qb =
      Q + ((size_t)(b * 16 + h) * 2048 + qt * 128 + wave * 32) * 128;
  bf16x8 qf[8];
#pragma unroll
  for (int s = 0; s < 8; ++s)
    qf[s] = *(const bf16x8*)(Qb + l31 * 128 + s * 16 + hi * 8);
  f32x16 acc[4], acc4;
#pragma unroll
  for (int c = 0; c < 4; ++c)
#pragma unroll
    for (int r = 0; r < 16; ++r) acc[c][r] = 0.f;
#pragma unroll
  for (int r = 0; r < 16; ++r) acc4[r] = 0.f;
  bf16x8 ones;
#pragma unroll
  for (int i = 0; i < 8; ++i) ones[i] = (short)0x3F80;  // bf16 1.0

  auto stage = [&](int t) {  // 8 async DMA: K 16KB + V 16KB into buf t&1
    const char* kt = Kt + (size_t)t * 16384;
    const char* vt = Vt + (size_t)t * 16384;
    char* kd = (char*)Kl[t & 1];
    char* vd = (char*)Vl[t & 1];
#pragma unroll
    for (int c = 0; c < 4; ++c) {
      gload_lds16(kt + c * 4096 + tid * 16, kd + c * 4096 + wave * 1024);
      gload_lds16(vt + c * 4096 + tid * 16, vd + c * 4096 + wave * 1024);
    }
  };

  auto qk = [&](int t, f32x16& s0, f32x16& s1) {  // frag-major: contiguous, 0-conflict
    const char* Kb = (const char*)Kl[t & 1] + hi * 1024 + l31 * 16;
#pragma unroll
    for (int r = 0; r < 16; ++r) { s0[r] = 0.f; s1[r] = 0.f; }
    __builtin_amdgcn_s_setprio(1);
#pragma unroll
    for (int s = 0; s < 8; ++s) {
      bf16x8 k0 = *(const bf16x8*)(Kb + s * 2048);
      bf16x8 k1 = *(const bf16x8*)(Kb + s * 2048 + 512);
      s0 = __builtin_amdgcn_mfma_f32_32x32x16_bf16(k0, qf[s], s0, 0, 0, 0);
      s1 = __builtin_amdgcn_mfma_f32_32x32x16_bf16(k1, qf[s], s1, 0, 0, 0);
    }
    __builtin_amdgcn_s_setprio(0);
  };

  // half(t): exp2/pack | bar1 | PV(t)+sum(t) | bar2 | stage(t+2) | qk(t+1)->N
  auto half = [&](int t, f32x16& c0, f32x16& c1, f32x16& n0_, f32x16& n1_) {
    float p0[16], p1[16];
#pragma unroll
    for (int r = 0; r < 16; ++r) {
      p0[r] = exp2f(c0[r]);
      p1[r] = exp2f(c1[r]);
    }
    union { bf16x8 v[4]; unsigned w[16]; } pa;
#pragma unroll
    for (int r = 0; r < 4; ++r) {
      pa.w[r]      = cvt_pk_bf16(p0[2 * r], p0[2 * r + 1]);
      pa.w[4 + r]  = cvt_pk_bf16(p0[8 + 2 * r], p0[9 + 2 * r]);
      pa.w[8 + r]  = cvt_pk_bf16(p1[2 * r], p1[2 * r + 1]);
      pa.w[12 + r] = cvt_pk_bf16(p1[8 + 2 * r], p1[9 + 2 * r]);
    }
    __syncthreads();  // bar1: tile t+1 resident (staged 1.5 tiles ago)
    const char* Vb = (const char*)Vl[t & 1];
    __builtin_amdgcn_s_setprio(1);
#pragma unroll
    for (int p = 0; p < 4; ++p) {
#pragma unroll
      for (int c = 0; c < 4; ++c) {
        bf16x8 vf = *(const bf16x8*)(Vb + p * 4096 + c * 1024 + hi * 512 + l31 * 16);
        acc[c] = __builtin_amdgcn_mfma_f32_32x32x16_bf16(pa.v[p], vf, acc[c], 0, 0, 0);
      }
      acc4 = __builtin_amdgcn_mfma_f32_32x32x16_bf16(pa.v[p], ones, acc4, 0, 0, 0);
    }
    __builtin_amdgcn_s_setprio(0);
    __syncthreads();  // bar2: all waves done reading buf t
    if (t + 2 < 32) stage(t + 2);            // overwrites buf t&1
    __builtin_amdgcn_sched_barrier(0);       // keep DMA issue ahead of qk's ds_reads
    if (t + 1 < 32) qk(t + 1, n0_, n1_);     // long prefetch window for stage(t+2)
  };

  // prologue
  stage(0);
  __syncthreads();
  f32x16 sA0, sA1, sB0, sB1;
  qk(0, sA0, sA1);
  stage(1);

  for (int t = 0; t < 32; t += 2) {
    half(t, sA0, sA1, sB0, sB1);
    half(t + 1, sB0, sB1, sA0, sA1);
  }

  // epilogue: acc[c][r] = N[q][d=c*32+l31], acc4[r] = lsum[q] (same lane, same r)
#pragma unroll
  for (int r = 0; r < 16; ++r) {
    int q = (r & 3) + 8 * (r >> 2) + 4 * hi;
    float invq = 1.0f / acc4[r];
    int srow = qt * 128 + wave * 32 + q;
    unsigned short* dst = O + (((size_t)b * 2048 + srow) * 16 + h) * 128;
#pragma unroll
    for (int c = 0; c < 4; ++c)
      dst[c * 32 + l31] = f2bf(acc[c][r] * invq);
  }
}

extern "C" void kernel_launch(void* const* d_in, const int* in_sizes, int n_in,
                              void* d_out, int out_size, void* d_ws, size_t ws_size,
                              hipStream_t stream) {
  const float* hs   = (const float*)d_in[0];
  const float* cosT = (const float*)d_in[1];
  const float* sinT = (const float*)d_in[2];
  const float* Wq   = (const float*)d_in[3];
  const float* Wk   = (const float*)d_in[4];
  const float* Wv   = (const float*)d_in[5];
  const float* Wo   = (const float*)d_in[6];
  const float* nqw  = (const float*)d_in[7];
  const float* nkw  = (const float*)d_in[8];
  float* out = (float*)d_out;

  char* ws = (char*)d_ws;
  unsigned short* X    = (unsigned short*)ws;               // 4096x2048 bf16
  unsigned short* Wqkv = X + 8388608;                       // 3072x2048 bf16
  unsigned short* WoB  = Wqkv + 6291456;                    // 2048x2048 bf16
  unsigned short* QKVb = WoB + 4194304;                     // 4096x3072 bf16
  unsigned short* Qb   = QKVb + 12582912;                   // (B,H,S,D)
  unsigned short* Kg   = Qb + 8388608;                      // K tiles 4.19MB
  unsigned short* Vg   = Kg + 2097152;                      // V tiles 4.19MB
  unsigned short* Ob   = QKVb;                              // reuse QKVb (dead)

  cvt_all<<<18432, 256, 0, stream>>>((const float4*)hs, (const float4*)Wq,
                                     (const float4*)Wk, (const float4*)Wv,
                                     (const float4*)Wo, (ushort4*)X,
                                     (ushort4*)Wqkv, (ushort4*)WoB);

  // QKV = X @ Wqkv^T : 256x192 tiles -> 16x16 = 256 blocks, bf16 out
  gemm_bt_8ph<3, true><<<256, 512, 0, stream>>>(X, Wqkv, QKVb, 4096, 3072, 2048);

  rms_rope<<<24576, 256, 0, stream>>>(QKVb, cosT, sinT, nqw, nkw, Qb, Kg, Vg);

  attn64<<<512, 256, 0, stream>>>(Qb, Kg, Vg, Ob);

  // out = O @ Wo^T : 256x128 tiles -> 16x16 = 256 blocks, f32 out
  gemm_bt_8ph<2, false><<<256, 512, 0, stream>>>(Ob, WoB, out, 4096, 2048, 2048);
}